// Round 1
// baseline (313.160 us; speedup 1.0000x reference)
//
#include <hip/hip_runtime.h>
#include <math.h>
#include <stdint.h>

#define TOPK 8
#define NEXP 256

// monotone map: float -> uint32 such that a<b (IEEE) <=> fmap(a)<fmap(b)
__device__ __forceinline__ uint32_t fmap(float v) {
  uint32_t b = __float_as_uint(v);
  uint32_t m = (uint32_t)((int32_t)b >> 31) | 0x80000000u;
  return b ^ m;
}
__device__ __forceinline__ float funmap(uint32_t k) {
  uint32_t b = (k & 0x80000000u) ? (k ^ 0x80000000u) : ~k;
  return __uint_as_float(b);
}

// branchless sorted-insert (descending) of (key,idx) into K[8]/I[8].
// strict '>' so equal keys keep earlier index first (jax top_k tie-break).
// r9 accumulates the max displaced key == 9th-largest overall.
#define INSERT8(kk, ii)                                   \
  {                                                       \
    uint32_t _k = (kk); uint32_t _i = (ii);               \
    _Pragma("unroll")                                     \
    for (int _s = 0; _s < TOPK; ++_s) {                   \
      bool _t = _k > K[_s];                               \
      uint32_t _ok = K[_s]; uint32_t _oi = I[_s];         \
      K[_s] = _t ? _k : _ok; I[_s] = _t ? _i : _oi;       \
      _k = _t ? _ok : _k;   _i = _t ? _oi : _i;           \
    }                                                     \
    r9 = (r9 > _k) ? r9 : _k;                             \
  }

__global__ __launch_bounds__(256, 4)
void moe_route_kernel(const float* __restrict__ logits,
                      const float* __restrict__ bias,
                      float* __restrict__ out_idx,
                      float* __restrict__ out_w,
                      int T)
{
  // 4 waves * 64 rows * 8 float4-slots = 32 KB, XOR-swizzled (no pad needed)
  __shared__ float4 tile[4 * 64 * 8];

  const int tid  = threadIdx.x;
  const int lane = tid & 63;
  const int wave = tid >> 6;
  const int r0   = blockIdx.x * 256 + wave * 64;
  const int myrow = r0 + lane;
  float4* wlds = tile + wave * 512;

  uint32_t K[TOPK], I[TOPK];
#pragma unroll
  for (int i = 0; i < TOPK; ++i) { K[i] = 0u; I[i] = 0u; }
  uint32_t r9 = 0u;

  const int lrow8 = lane >> 3;  // which of 8 rows this lane stages per iter
  const int c4l   = lane & 7;   // which float4 column chunk

  for (int t = 0; t < 8; ++t) {          // 8 column tiles of 32
    const int c0 = t * 32;
    // ---- stage: coalesced global float4 -> swizzled LDS ----
#pragma unroll
    for (int it = 0; it < 8; ++it) {
      const int rl = it * 8 + lrow8;     // local row 0..63
      const int grow = r0 + rl;
      float4 v = make_float4(0.f, 0.f, 0.f, 0.f);
      if (grow < T)
        v = *(const float4*)(logits + (size_t)grow * NEXP + (c0 + c4l * 4));
      wlds[rl * 8 + (c4l ^ (rl & 7))] = v;
    }
    __syncthreads();
    // ---- consume: lane reads its own row, b128, bank-spread by swizzle ----
#pragma unroll
    for (int j = 0; j < 8; ++j) {
      const float4 x = wlds[lane * 8 + (j ^ (lane & 7))];
      const int cb = c0 + j * 4;
      const float4 bb = *(const float4*)(bias + cb);   // wave-uniform -> s_load
      {
        float e = __expf(-x.x); float d = 1.f + e;
        float inv = __builtin_amdgcn_rcpf(d); inv = inv * fmaf(-d, inv, 2.f);
        INSERT8(fmap(inv + bb.x), (uint32_t)(cb + 0));
      }
      {
        float e = __expf(-x.y); float d = 1.f + e;
        float inv = __builtin_amdgcn_rcpf(d); inv = inv * fmaf(-d, inv, 2.f);
        INSERT8(fmap(inv + bb.y), (uint32_t)(cb + 1));
      }
      {
        float e = __expf(-x.z); float d = 1.f + e;
        float inv = __builtin_amdgcn_rcpf(d); inv = inv * fmaf(-d, inv, 2.f);
        INSERT8(fmap(inv + bb.z), (uint32_t)(cb + 2));
      }
      {
        float e = __expf(-x.w); float d = 1.f + e;
        float inv = __builtin_amdgcn_rcpf(d); inv = inv * fmaf(-d, inv, 2.f);
        INSERT8(fmap(inv + bb.w), (uint32_t)(cb + 3));
      }
    }
    __syncthreads();
  }

  // ---- ambiguity check over the sorted top-9: min adjacent gap ----
  float prev = funmap(K[0]);
  float ming = 1e30f;
#pragma unroll
  for (int i = 1; i < TOPK; ++i) {
    float vi = funmap(K[i]);
    ming = fminf(ming, prev - vi);
    prev = vi;
  }
  ming = fminf(ming, prev - funmap(r9));

  if (myrow < T) {
    if (ming < 4e-6f) {
      // rare precise redo: correctly-rounded f32 sigmoid via double
#pragma unroll
      for (int i = 0; i < TOPK; ++i) { K[i] = 0u; I[i] = 0u; }
      const float* rowp = logits + (size_t)myrow * NEXP;
      for (int c = 0; c < NEXP; ++c) {
        float x = rowp[c];
        double sd = 1.0 / (1.0 + exp(-(double)x));
        float swb = (float)sd + bias[c];
        INSERT8(fmap(swb), (uint32_t)c);
      }
    }
    // ---- epilogue: recover unbiased sigmoid, normalize, store ----
    float s[TOPK]; float sum = 0.f;
#pragma unroll
    for (int i = 0; i < TOPK; ++i) {
      float swb = funmap(K[i]);
      float sg = swb - bias[I[i]];   // sigmoid back out (ulp-level error ok)
      s[i] = sg; sum += sg;
    }
    float innv = 1.0f / (sum + 1e-20f);
    float4 oa = make_float4((float)I[0], (float)I[1], (float)I[2], (float)I[3]);
    float4 ob = make_float4((float)I[4], (float)I[5], (float)I[6], (float)I[7]);
    float4 wa = make_float4(s[0]*innv, s[1]*innv, s[2]*innv, s[3]*innv);
    float4 wb = make_float4(s[4]*innv, s[5]*innv, s[6]*innv, s[7]*innv);
    float* po = out_idx + (size_t)myrow * 8;
    float* pw = out_w   + (size_t)myrow * 8;
    *(float4*)(po)     = oa;
    *(float4*)(po + 4) = ob;
    *(float4*)(pw)     = wa;
    *(float4*)(pw + 4) = wb;
  }
}

extern "C" void kernel_launch(void* const* d_in, const int* in_sizes, int n_in,
                              void* d_out, int out_size, void* d_ws, size_t ws_size,
                              hipStream_t stream) {
  const float* logits = (const float*)d_in[0];
  const float* bias   = (const float*)d_in[1];
  const int T = in_sizes[0] / NEXP;
  float* out    = (float*)d_out;
  float* out_idx = out;
  float* out_w   = out + (size_t)T * TOPK;
  const int blocks = (T + 255) / 256;
  moe_route_kernel<<<blocks, 256, 0, stream>>>(logits, bias, out_idx, out_w, T);
}

// Round 2
// 299.740 us; speedup vs baseline: 1.0448x; 1.0448x over previous
//
#include <hip/hip_runtime.h>
#include <math.h>
#include <stdint.h>

#define TOPK 8
#define NEXP 256

// monotone map: float -> uint32 such that a<b (IEEE) <=> fmap(a)<fmap(b)
__device__ __forceinline__ uint32_t fmap(float v) {
  uint32_t b = __float_as_uint(v);
  uint32_t m = (uint32_t)((int32_t)b >> 31) | 0x80000000u;
  return b ^ m;
}
__device__ __forceinline__ float funmap(uint32_t k) {
  uint32_t b = (k & 0x80000000u) ? (k ^ 0x80000000u) : ~k;
  return __uint_as_float(b);
}

// tie-break comparator: larger key wins; equal keys -> smaller index wins
__device__ __forceinline__ bool gtr(uint32_t ka, uint32_t ia, uint32_t kb, uint32_t ib) {
  return (ka > kb) || (ka == kb && ia < ib);
}

// branchless sorted-insert (descending) of (key,idx) into K[8]/I[8].
// strict '>' keeps earlier (smaller, since processed ascending) index first.
// r9 accumulates the max displaced key == 9th-largest seen.
#define INSERT8(kk, ii)                                   \
  {                                                       \
    uint32_t _k = (kk); uint32_t _i = (ii);               \
    _Pragma("unroll")                                     \
    for (int _s = 0; _s < TOPK; ++_s) {                   \
      bool _t = _k > K[_s];                               \
      uint32_t _ok = K[_s]; uint32_t _oi = I[_s];         \
      K[_s] = _t ? _k : _ok; I[_s] = _t ? _i : _oi;       \
      _k = _t ? _ok : _k;   _i = _t ? _oi : _i;           \
    }                                                     \
    r9 = (r9 > _k) ? r9 : _k;                             \
  }

__global__ __launch_bounds__(256, 6)
void moe_route_kernel(const float* __restrict__ logits,
                      const float* __restrict__ bias,
                      float* __restrict__ out_idx,
                      float* __restrict__ out_w,
                      int T)
{
  // 64 rows x 16 float4-slots (64 cols), XOR-swizzled: 16 KB/block
  __shared__ float4 tile[1024];

  const int tid  = threadIdx.x;
  const int lane = tid & 63;
  const int wave = tid >> 6;
  const int q    = lane & 3;                 // quad position: 4 lanes / row
  const int lrow = wave * 16 + (lane >> 2);  // block-local row 0..63
  const int r0   = blockIdx.x * 64;
  const int grow = r0 + lrow;

  uint32_t K[TOPK], I[TOPK];
#pragma unroll
  for (int i = 0; i < TOPK; ++i) { K[i] = 0u; I[i] = 0u; }
  uint32_t r9 = 0u;

  for (int t = 0; t < 4; ++t) {              // 4 column tiles of 64
    const int c0 = t * 64;
    // ---- stage: coalesced global float4 -> swizzled LDS ----
#pragma unroll
    for (int k = 0; k < 4; ++k) {
      const int f  = tid + k * 256;          // 0..1023 flat float4 index
      const int rl = f >> 4;                 // local row 0..63
      const int c4 = f & 15;                 // float4 column chunk
      float4 v = make_float4(0.f, 0.f, 0.f, 0.f);
      const int gr = r0 + rl;
      if (gr < T)
        v = *(const float4*)(logits + (size_t)gr * NEXP + (c0 + c4 * 4));
      tile[rl * 16 + (c4 ^ (rl & 15))] = v;
    }
    __syncthreads();
    // ---- consume: lane q of each quad takes column chunks q*4+j ----
#pragma unroll
    for (int j = 0; j < 4; ++j) {
      const int slot = (q * 4 + j) ^ (lrow & 15);
      const float4 x = tile[lrow * 16 + slot];
      const int cb = c0 + q * 16 + j * 4;    // expert index base
      const float4 bb = *(const float4*)(bias + cb);
      {
        float e = __expf(-x.x); float d = 1.f + e;
        float inv = __builtin_amdgcn_rcpf(d); inv = inv * fmaf(-d, inv, 2.f);
        INSERT8(fmap(inv + bb.x), (uint32_t)(cb + 0));
      }
      {
        float e = __expf(-x.y); float d = 1.f + e;
        float inv = __builtin_amdgcn_rcpf(d); inv = inv * fmaf(-d, inv, 2.f);
        INSERT8(fmap(inv + bb.y), (uint32_t)(cb + 1));
      }
      {
        float e = __expf(-x.z); float d = 1.f + e;
        float inv = __builtin_amdgcn_rcpf(d); inv = inv * fmaf(-d, inv, 2.f);
        INSERT8(fmap(inv + bb.z), (uint32_t)(cb + 2));
      }
      {
        float e = __expf(-x.w); float d = 1.f + e;
        float inv = __builtin_amdgcn_rcpf(d); inv = inv * fmaf(-d, inv, 2.f);
        INSERT8(fmap(inv + bb.w), (uint32_t)(cb + 3));
      }
    }
    __syncthreads();
  }

  // ---- merge the 4 per-lane sorted-8 lists across the quad (replicated) ----
#pragma unroll
  for (int mstep = 0; mstep < 2; ++mstep) {
    const int mask = 1 << mstep;
    uint32_t Kp[TOPK], Ip[TOPK];
#pragma unroll
    for (int i = 0; i < TOPK; ++i) {
      Kp[i] = (uint32_t)__shfl_xor((int)K[i], mask, 64);
      Ip[i] = (uint32_t)__shfl_xor((int)I[i], mask, 64);
    }
    const uint32_t r9p = (uint32_t)__shfl_xor((int)r9, mask, 64);
    uint32_t M[TOPK], MI[TOPK];
    uint32_t lo = 0u;
#pragma unroll
    for (int i = 0; i < TOPK; ++i) {
      const uint32_t kb = Kp[7 - i], ib = Ip[7 - i];
      const bool g = gtr(K[i], I[i], kb, ib);
      M[i]  = g ? K[i] : kb;
      MI[i] = g ? I[i] : ib;
      const uint32_t losr = g ? kb : K[i];
      lo = lo > losr ? lo : losr;             // max of discarded = union 9th
    }
    r9 = r9 > r9p ? r9 : r9p;
    r9 = r9 > lo ? r9 : lo;
    // bitonic sort-8 (input is bitonic), descending, with tie-break
#define CE(a, b)                                                        \
    { const bool g = gtr(M[a], MI[a], M[b], MI[b]);                     \
      const uint32_t k1 = g ? M[a] : M[b], k2 = g ? M[b] : M[a];        \
      const uint32_t i1 = g ? MI[a] : MI[b], i2 = g ? MI[b] : MI[a];    \
      M[a] = k1; M[b] = k2; MI[a] = i1; MI[b] = i2; }
    CE(0,4) CE(1,5) CE(2,6) CE(3,7)
    CE(0,2) CE(1,3) CE(4,6) CE(5,7)
    CE(0,1) CE(2,3) CE(4,5) CE(6,7)
#undef CE
#pragma unroll
    for (int i = 0; i < TOPK; ++i) { K[i] = M[i]; I[i] = MI[i]; }
  }

  // ---- ambiguity check: min adjacent gap over sorted top-8 + 9th ----
  float prev = funmap(K[0]);
  float ming = 1e30f;
#pragma unroll
  for (int i = 1; i < TOPK; ++i) {
    const float vi = funmap(K[i]);
    ming = fminf(ming, prev - vi);
    prev = vi;
  }
  ming = fminf(ming, prev - funmap(r9));

  // ---- rare precise redo on quad leader: correctly-rounded f32 sigmoid ----
  if (grow < T && q == 0 && ming < 4e-6f) {
#pragma unroll
    for (int i = 0; i < TOPK; ++i) { K[i] = 0u; I[i] = 0u; }
    const float* rowp = logits + (size_t)grow * NEXP;
    for (int c = 0; c < NEXP; ++c) {
      const float x = rowp[c];
      const double sd = 1.0 / (1.0 + exp(-(double)x));
      const float swb = (float)sd + bias[c];
      INSERT8(fmap(swb), (uint32_t)c);
    }
  }
  // broadcast leader's (possibly corrected) result to the quad
  const int leader = lane & ~3;
#pragma unroll
  for (int i = 0; i < TOPK; ++i) {
    K[i] = (uint32_t)__shfl((int)K[i], leader, 64);
    I[i] = (uint32_t)__shfl((int)I[i], leader, 64);
  }

  // ---- epilogue: each quad lane writes one float4 quarter ----
  if (grow < T) {
    float* const po = out_idx + (size_t)grow * 8;
    float* const pw = out_w   + (size_t)grow * 8;
    if (q == 0) {
      *(float4*)po = make_float4((float)I[0], (float)I[1], (float)I[2], (float)I[3]);
    } else if (q == 1) {
      *(float4*)(po + 4) = make_float4((float)I[4], (float)I[5], (float)I[6], (float)I[7]);
    } else {
      float s[TOPK]; float sum = 0.f;
#pragma unroll
      for (int i = 0; i < TOPK; ++i) {
        const float sg = funmap(K[i]) - bias[I[i]];  // unbiased sigmoid back out
        s[i] = sg; sum += sg;
      }
      const float innv = 1.0f / (sum + 1e-20f);
      if (q == 2)
        *(float4*)pw = make_float4(s[0]*innv, s[1]*innv, s[2]*innv, s[3]*innv);
      else
        *(float4*)(pw + 4) = make_float4(s[4]*innv, s[5]*innv, s[6]*innv, s[7]*innv);
    }
  }
}

extern "C" void kernel_launch(void* const* d_in, const int* in_sizes, int n_in,
                              void* d_out, int out_size, void* d_ws, size_t ws_size,
                              hipStream_t stream) {
  const float* logits = (const float*)d_in[0];
  const float* bias   = (const float*)d_in[1];
  const int T = in_sizes[0] / NEXP;
  float* out     = (float*)d_out;
  float* out_idx = out;
  float* out_w   = out + (size_t)T * TOPK;
  const int blocks = (T + 63) / 64;
  moe_route_kernel<<<blocks, 256, 0, stream>>>(logits, bias, out_idx, out_w, T);
}

// Round 3
// 297.106 us; speedup vs baseline: 1.0540x; 1.0089x over previous
//
#include <hip/hip_runtime.h>
#include <math.h>
#include <stdint.h>

#define TOPK 8
#define NEXP 256

// monotone map: float -> uint32 such that a<b (IEEE) <=> fmap(a)<fmap(b)
__device__ __forceinline__ uint32_t fmap(float v) {
  uint32_t b = __float_as_uint(v);
  uint32_t m = (uint32_t)((int32_t)b >> 31) | 0x80000000u;
  return b ^ m;
}
__device__ __forceinline__ float funmap(uint32_t k) {
  uint32_t b = (k & 0x80000000u) ? (k ^ 0x80000000u) : ~k;
  return __uint_as_float(b);
}

// tie-break comparator: larger key wins; equal keys -> smaller index wins
__device__ __forceinline__ bool gtr(uint32_t ka, uint32_t ia, uint32_t kb, uint32_t ib) {
  return (ka > kb) || (ka == kb && ia < ib);
}

// branchless sorted-insert (descending) of (key,idx) into K[8]/I[8].
// strict '>' keeps earlier (smaller, since processed ascending) index first.
// r9 accumulates the max displaced key == 9th-largest seen.
#define INSERT8(kk, ii)                                   \
  {                                                       \
    uint32_t _k = (kk); uint32_t _i = (ii);               \
    _Pragma("unroll")                                     \
    for (int _s = 0; _s < TOPK; ++_s) {                   \
      bool _t = _k > K[_s];                               \
      uint32_t _ok = K[_s]; uint32_t _oi = I[_s];         \
      K[_s] = _t ? _k : _ok; I[_s] = _t ? _i : _oi;       \
      _k = _t ? _ok : _k;   _i = _t ? _oi : _i;           \
    }                                                     \
    r9 = (r9 > _k) ? r9 : _k;                             \
  }

#define SIGMOID_INSERT(xv, bv, ci)                                        \
  {                                                                       \
    float _e = __expf(-(xv)); float _d = 1.f + _e;                        \
    float _inv = __builtin_amdgcn_rcpf(_d);                               \
    _inv = _inv * fmaf(-_d, _inv, 2.f);                                   \
    INSERT8(fmap(_inv + (bv)), (uint32_t)(ci));                           \
  }

__global__ __launch_bounds__(256, 4)
void moe_route_kernel(const float* __restrict__ logits,
                      const float* __restrict__ bias,
                      float* __restrict__ out_idx,
                      float* __restrict__ out_w,
                      int T)
{
  const int tid  = threadIdx.x;
  const int lane = tid & 63;
  const int q    = lane & 3;                      // quad position: 4 lanes / row
  const int grow = blockIdx.x * 64 + (tid >> 2);  // global row for this lane
  const int rrow = grow < T ? grow : (T - 1);     // clamp so whole wave stays active

  const float4* __restrict__ rowp4  = (const float4*)(logits + (size_t)rrow * NEXP);
  const float4* __restrict__ bias4  = (const float4*)bias;

  uint32_t K[TOPK], I[TOPK];
#pragma unroll
  for (int i = 0; i < TOPK; ++i) { K[i] = 0u; I[i] = 0u; }
  uint32_t r9 = 0u;

  // lane owns float4 chunks q + 4k (experts 4q+16k .. +4): each step the quad
  // covers one full 64B line per row -> sector-perfect, no LDS, no barriers.
  float4 x = rowp4[q];
#pragma unroll
  for (int k = 0; k < 16; ++k) {
    float4 xn;
    if (k < 15) xn = rowp4[q + 4 * (k + 1)];      // depth-2 register pipeline
    const float4 bb = bias4[q + 4 * k];           // 1KB, L1-resident
    const int cb = 4 * q + 16 * k;
    SIGMOID_INSERT(x.x, bb.x, cb + 0);
    SIGMOID_INSERT(x.y, bb.y, cb + 1);
    SIGMOID_INSERT(x.z, bb.z, cb + 2);
    SIGMOID_INSERT(x.w, bb.w, cb + 3);
    x = xn;
  }

  // ---- merge the 4 per-lane sorted-8 lists across the quad (replicated) ----
#pragma unroll
  for (int mstep = 0; mstep < 2; ++mstep) {
    const int mask = 1 << mstep;
    uint32_t Kp[TOPK], Ip[TOPK];
#pragma unroll
    for (int i = 0; i < TOPK; ++i) {
      Kp[i] = (uint32_t)__shfl_xor((int)K[i], mask, 64);
      Ip[i] = (uint32_t)__shfl_xor((int)I[i], mask, 64);
    }
    const uint32_t r9p = (uint32_t)__shfl_xor((int)r9, mask, 64);
    uint32_t M[TOPK], MI[TOPK];
    uint32_t lo = 0u;
#pragma unroll
    for (int i = 0; i < TOPK; ++i) {
      const uint32_t kb = Kp[7 - i], ib = Ip[7 - i];
      const bool g = gtr(K[i], I[i], kb, ib);
      M[i]  = g ? K[i] : kb;
      MI[i] = g ? I[i] : ib;
      const uint32_t losr = g ? kb : K[i];
      lo = lo > losr ? lo : losr;             // max of discarded = union 9th
    }
    r9 = r9 > r9p ? r9 : r9p;
    r9 = r9 > lo ? r9 : lo;
    // bitonic sort-8 (input is bitonic), descending, with tie-break
#define CE(a, b)                                                        \
    { const bool g = gtr(M[a], MI[a], M[b], MI[b]);                     \
      const uint32_t k1 = g ? M[a] : M[b], k2 = g ? M[b] : M[a];        \
      const uint32_t i1 = g ? MI[a] : MI[b], i2 = g ? MI[b] : MI[a];    \
      M[a] = k1; M[b] = k2; MI[a] = i1; MI[b] = i2; }
    CE(0,4) CE(1,5) CE(2,6) CE(3,7)
    CE(0,2) CE(1,3) CE(4,6) CE(5,7)
    CE(0,1) CE(2,3) CE(4,5) CE(6,7)
#undef CE
#pragma unroll
    for (int i = 0; i < TOPK; ++i) { K[i] = M[i]; I[i] = MI[i]; }
  }

  // ---- ambiguity check: min adjacent gap over sorted top-8 + 9th ----
  float prev = funmap(K[0]);
  float ming = 1e30f;
#pragma unroll
  for (int i = 1; i < TOPK; ++i) {
    const float vi = funmap(K[i]);
    ming = fminf(ming, prev - vi);
    prev = vi;
  }
  ming = fminf(ming, prev - funmap(r9));

  // ---- rare precise redo on quad leader: correctly-rounded f32 sigmoid ----
  if (grow < T && q == 0 && ming < 4e-6f) {
#pragma unroll
    for (int i = 0; i < TOPK; ++i) { K[i] = 0u; I[i] = 0u; }
    const float* rowp = logits + (size_t)grow * NEXP;
    for (int c = 0; c < NEXP; ++c) {
      const float x2 = rowp[c];
      const double sd = 1.0 / (1.0 + exp(-(double)x2));
      const float swb = (float)sd + bias[c];
      INSERT8(fmap(swb), (uint32_t)c);
    }
  }
  // broadcast leader's (possibly corrected) result to the quad
  const int leader = lane & ~3;
#pragma unroll
  for (int i = 0; i < TOPK; ++i) {
    K[i] = (uint32_t)__shfl((int)K[i], leader, 64);
    I[i] = (uint32_t)__shfl((int)I[i], leader, 64);
  }

  // ---- epilogue: each quad lane writes one float4 quarter ----
  if (grow < T) {
    float* const po = out_idx + (size_t)grow * 8;
    float* const pw = out_w   + (size_t)grow * 8;
    if (q == 0) {
      *(float4*)po = make_float4((float)I[0], (float)I[1], (float)I[2], (float)I[3]);
    } else if (q == 1) {
      *(float4*)(po + 4) = make_float4((float)I[4], (float)I[5], (float)I[6], (float)I[7]);
    } else {
      float s[TOPK]; float sum = 0.f;
#pragma unroll
      for (int i = 0; i < TOPK; ++i) {
        const float sg = funmap(K[i]) - bias[I[i]];  // unbiased sigmoid back out
        s[i] = sg; sum += sg;
      }
      const float innv = 1.0f / (sum + 1e-20f);
      if (q == 2)
        *(float4*)pw = make_float4(s[0]*innv, s[1]*innv, s[2]*innv, s[3]*innv);
      else
        *(float4*)(pw + 4) = make_float4(s[4]*innv, s[5]*innv, s[6]*innv, s[7]*innv);
    }
  }
}

extern "C" void kernel_launch(void* const* d_in, const int* in_sizes, int n_in,
                              void* d_out, int out_size, void* d_ws, size_t ws_size,
                              hipStream_t stream) {
  const float* logits = (const float*)d_in[0];
  const float* bias   = (const float*)d_in[1];
  const int T = in_sizes[0] / NEXP;
  float* out     = (float*)d_out;
  float* out_idx = out;
  float* out_w   = out + (size_t)T * TOPK;
  const int blocks = (T + 63) / 64;
  moe_route_kernel<<<blocks, 256, 0, stream>>>(logits, bias, out_idx, out_w, T);
}